// Round 7
// baseline (223.616 us; speedup 1.0000x reference)
//
#include <hip/hip_runtime.h>
#include <hip/hip_bf16.h>
#include <stdint.h>

// LightNet attention fwd. B=2, T=2048, HID=1024, H=8, DK=DV=128, LR=128.
// Contract (R1-R4): inputs fp32, output fp32.
//
// o_t[v] = scale * sum_k (q_t[k]/E_t[k]) * sum_{s<=t} e_s[k] v_s[v],
// e=exp(k), E=cumsum(e). Chunked Tc=128: pass1 (MFMA) Esum + Ut=(e^T V)^T;
// pass2 exclusive chunk prefix; pass3 (MFMA) intra(causal)+inter + row
// sum-of-squares for RMSNorm; out_gemm fuses RMSNorm*gnw*swish(gate) into
// the A-staging of the final projection.
// GEMMs: bf16 MFMA 128x128 tile, BK=64 (2x32 sub-tiles per barrier pair),
// global_load_lds width-16 staging, LDS-staged coalesced bf16 epilogue.

typedef short short8 __attribute__((ext_vector_type(8)));
typedef float f32x4 __attribute__((ext_vector_type(4)));

#define T_SEQ 2048
#define HIDN  1024
#define SCALE 0.08838834764831845f   // 128^-0.5
#define LDSP  136                    // padded LDS row stride (shorts)

// ---------------- bf16 bit helpers ----------------
__device__ __forceinline__ float blo(unsigned int u){
  union{unsigned int i; float f;} v; v.i = u << 16; return v.f;
}
__device__ __forceinline__ float bhi(unsigned int u){
  union{unsigned int i; float f;} v; v.i = u & 0xffff0000u; return v.f;
}
__device__ __forceinline__ float bu2f(unsigned short u){
  union{unsigned int i; float f;} v; v.i = ((unsigned int)u) << 16; return v.f;
}
__device__ __forceinline__ unsigned short f2bu(float f){
  union{float f; unsigned int i;} v; v.f = f;
  unsigned int x = v.i;
  x += 0x7fffu + ((x >> 16) & 1u);     // RNE
  return (unsigned short)(x >> 16);
}
__device__ __forceinline__ void up8(const unsigned short* p, float* f){
  uint4 v = *(const uint4*)p;
  f[0]=blo(v.x); f[1]=bhi(v.x); f[2]=blo(v.y); f[3]=bhi(v.y);
  f[4]=blo(v.z); f[5]=bhi(v.z); f[6]=blo(v.w); f[7]=bhi(v.w);
}
__device__ __forceinline__ void async16(const void* g, void* l){
  __builtin_amdgcn_global_load_lds(
      (const __attribute__((address_space(1))) unsigned int*)g,
      (__attribute__((address_space(3))) unsigned int*)l, 16, 0, 0);
}

// ---------------- fused input cast + SumSq zeroing ------------------------
// quads: X 1048576 | Wq/Wk/Wv/Wo 262144 ea | Wg1/Wg2 32768 ea | gnw 256
// = 2,162,944 = 8449 blocks; +4 blocks zero SumSq[4096] floats.
__global__ __launch_bounds__(256) void convert_all(
    const float* __restrict__ X,  const float* __restrict__ Wq,
    const float* __restrict__ Wk, const float* __restrict__ Wv,
    const float* __restrict__ Wg1,const float* __restrict__ Wg2,
    const float* __restrict__ gnw,const float* __restrict__ Wo,
    unsigned short* __restrict__ base, float* __restrict__ SumSq)
{
  int q = blockIdx.x * 256 + threadIdx.x;
  const float* src; unsigned short* dst; int rel = q;
  if (rel < 1048576)            { src = X;   dst = base;            }
  else if ((rel -= 1048576) < 262144) { src = Wq;  dst = base + 4194304; }
  else if ((rel -=  262144) < 262144) { src = Wk;  dst = base + 5242880; }
  else if ((rel -=  262144) < 262144) { src = Wv;  dst = base + 6291456; }
  else if ((rel -=  262144) < 262144) { src = Wo;  dst = base + 7340032; }
  else if ((rel -=  262144) <  32768) { src = Wg1; dst = base + 8388608; }
  else if ((rel -=   32768) <  32768) { src = Wg2; dst = base + 8519680; }
  else if ((rel -=   32768) <    256) { src = gnw; dst = base + 8650752; }
  else { rel -= 256;                              // zero SumSq (4096 floats)
    ((float4*)SumSq)[rel] = make_float4(0.f,0.f,0.f,0.f); return; }
  float4 v = ((const float4*)src)[rel];
  ushort4 o; o.x=f2bu(v.x); o.y=f2bu(v.y); o.z=f2bu(v.z); o.w=f2bu(v.w);
  ((ushort4*)dst)[rel] = o;
}

// ---------------- MFMA GEMM core: C(128x128)=A@B^T, BK=64 (2x32) ---------
// sA/sB: 128x64 shorts (16 KB each), two BK=32 sub-tiles at h*4096 shorts.
__device__ __forceinline__ void gemm_core(
    const unsigned short* __restrict__ A, const unsigned short* __restrict__ B,
    int K, int row0, int col0,
    unsigned short* sA, unsigned short* sB, f32x4 acc[4][4], int tid)
{
  const int lane = tid & 63;
  const int wm = (tid >> 6) & 1, wn = tid >> 7;
  const int wb = tid & 192;                // wave-uniform chunk base
  for (int k0 = 0; k0 < K; k0 += 64){
    __syncthreads();                       // prev iter's LDS reads done
#pragma unroll
    for (int h = 0; h < 2; ++h){
#pragma unroll
      for (int r = 0; r < 2; ++r){
        int idx  = r*256 + tid;            // 512 chunks of 16B per sub-tile
        int mrow = idx >> 2, kc = (idx & 3) * 8;
        async16(A + (size_t)(row0 + mrow)*K + k0 + h*32 + kc,
                sA + (size_t)(h*512 + r*256 + wb)*8);
        async16(B + (size_t)(col0 + mrow)*K + k0 + h*32 + kc,
                sB + (size_t)(h*512 + r*256 + wb)*8);
      }
    }
    __syncthreads();                       // drains vmcnt before barrier
#pragma unroll
    for (int h = 0; h < 2; ++h){
      short8 av[4], bv[4];
#pragma unroll
      for (int i=0;i<4;i++)
        av[i] = *(const short8*)(sA + h*4096 + (size_t)(wm*64 + i*16 + (lane&15))*32 + (lane>>4)*8);
#pragma unroll
      for (int j=0;j<4;j++)
        bv[j] = *(const short8*)(sB + h*4096 + (size_t)(wn*64 + j*16 + (lane&15))*32 + (lane>>4)*8);
#pragma unroll
      for (int i=0;i<4;i++)
#pragma unroll
        for (int j=0;j<4;j++)
          acc[i][j] = __builtin_amdgcn_mfma_f32_16x16x32_bf16(av[i], bv[j], acc[i][j], 0, 0, 0);
    }
  }
}

// bf16 epilogue via LDS: 4 passes of 32 rows; coalesced b128 copy-out.
__device__ __forceinline__ void epilogue_lds(
    f32x4 acc[4][4], int row0, int col0, int tid, int ldc, int act,
    unsigned short* __restrict__ Cb, unsigned short* sC)
{
  const int lane = tid & 63;
  const int wm = (tid >> 6) & 1, wn = tid >> 7;
#pragma unroll
  for (int p=0;p<4;p++){
    __syncthreads();
    if (wm == (p>>1)){
#pragma unroll
      for (int ii=0; ii<2; ii++){
        int i = (p&1)*2 + ii;
        int lr = i*16 + ((lane>>4)<<2) - (p&1)*32;   // local row in [0,32)
#pragma unroll
        for (int j=0;j<4;j++){
          int col = wn*64 + j*16 + (lane&15);
#pragma unroll
          for (int r=0;r<4;r++){
            float v = acc[i][j][r];
            if (act) v = v / (1.f + __expf(-v));
            sC[(lr+r)*128 + col] = f2bu(v);
          }
        }
      }
    }
    __syncthreads();
#pragma unroll
    for (int c = tid; c < 512; c += 256){  // 32 rows x 256B
      int rr = c >> 4, off = (c & 15)*8;
      *(uint4*)&Cb[(size_t)(row0 + p*32 + rr)*ldc + col0 + off] =
          *(const uint4*)&sC[rr*128 + off];
    }
  }
}

// fp32 direct epilogue (64B full-line segments).
__device__ __forceinline__ void epilogue_f32(
    f32x4 acc[4][4], int row0, int col0, int tid, int ldc,
    float* __restrict__ Cf)
{
  const int lane = tid & 63;
  const int wm = (tid >> 6) & 1, wn = tid >> 7;
#pragma unroll
  for (int i=0;i<4;i++){
    int rbase = row0 + wm*64 + i*16 + ((lane>>4)<<2);
#pragma unroll
    for (int j=0;j<4;j++){
      int col = col0 + wn*64 + j*16 + (lane&15);
#pragma unroll
      for (int r=0;r<4;r++)
        Cf[(size_t)(rbase + r)*ldc + col] = acc[i][j][r];
    }
  }
}

// Fused QKV+G1 projection. grid (32, 25).
__global__ __launch_bounds__(256, 2) void proj_kernel(
    const unsigned short* __restrict__ X,
    const unsigned short* __restrict__ Wq, const unsigned short* __restrict__ Wk,
    const unsigned short* __restrict__ Wv, const unsigned short* __restrict__ Wg1,
    unsigned short* __restrict__ Qb, unsigned short* __restrict__ Kb,
    unsigned short* __restrict__ Vb, unsigned short* __restrict__ G1b)
{
  __shared__ unsigned short sA[128*64], sB[128*64];
  int tid = threadIdx.x;
  int which = blockIdx.y >> 3;
  const unsigned short* Bp = (which==0)?Wq:(which==1)?Wk:(which==2)?Wv:Wg1;
  int row0 = blockIdx.x * 128;
  int col0 = (which==3) ? 0 : (blockIdx.y & 7) * 128;
  f32x4 acc[4][4] = {};
  gemm_core(X, Bp, HIDN, row0, col0, sA, sB, acc, tid);
  if      (which==0) epilogue_lds(acc,row0,col0,tid,HIDN,1,Qb, sA);
  else if (which==1) epilogue_lds(acc,row0,col0,tid,HIDN,0,Kb, sA);
  else if (which==2) epilogue_lds(acc,row0,col0,tid,HIDN,0,Vb, sA);
  else               epilogue_lds(acc,row0,col0,tid,128 ,0,G1b,sA);
}

// Generic A@B^T -> bf16 (gate path: act=1 swish).
__global__ __launch_bounds__(256, 2) void gemm_bt(
    const unsigned short* __restrict__ A, const unsigned short* __restrict__ B,
    int K, int ldc, int act, unsigned short* __restrict__ Cb)
{
  __shared__ unsigned short sA[128*64], sB[128*64];
  int tid = threadIdx.x;
  int row0 = blockIdx.x * 128, col0 = blockIdx.y * 128;
  f32x4 acc[4][4] = {};
  gemm_core(A, B, K, row0, col0, sA, sB, acc, tid);
  epilogue_lds(acc, row0, col0, tid, ldc, act, Cb, sA);
}

// Final fused GEMM: Out = (RMSNorm(Oatt)*gnw*Gt) @ Wo^T, fp32 out.
// A staged via registers (normalize+gate on the fly), B via global_load_lds.
__global__ __launch_bounds__(256, 2) void out_gemm(
    const unsigned short* __restrict__ Oatt, const unsigned short* __restrict__ Gt,
    const unsigned short* __restrict__ gnw,  const float* __restrict__ SumSq,
    const unsigned short* __restrict__ Wo,   float* __restrict__ Out)
{
  __shared__ unsigned short sA[128*64], sB[128*64];
  int tid = threadIdx.x;
  int row0 = blockIdx.x * 128, col0 = blockIdx.y * 128;
  const int wb = tid & 192;
  f32x4 acc[4][4] = {};
  const int lane = tid & 63;
  const int wm = (tid >> 6) & 1, wn = tid >> 7;
  for (int k0 = 0; k0 < HIDN; k0 += 64){
    __syncthreads();
#pragma unroll
    for (int h = 0; h < 2; ++h){
#pragma unroll
      for (int r = 0; r < 2; ++r){
        int idx  = r*256 + tid;
        int mrow = idx >> 2, kc = (idx & 3) * 8;
        async16(Wo + (size_t)(col0 + mrow)*HIDN + k0 + h*32 + kc,
                sB + (size_t)(h*512 + r*256 + wb)*8);
        // A: registers -> normalize/gate -> ds_write_b128
        int grow = row0 + mrow, gcol = k0 + h*32 + kc;
        float o[8], g[8], w[8];
        up8(&Oatt[(size_t)grow*HIDN + gcol], o);
        up8(&Gt  [(size_t)grow*HIDN + gcol], g);
        up8(&gnw[gcol], w);
        float rstd = rsqrtf(SumSq[grow]*(1.f/1024.f) + 1e-5f);
        unsigned short a8[8];
#pragma unroll
        for (int j=0;j<8;j++) a8[j] = f2bu(o[j]*rstd*w[j]*g[j]);
        *(uint4*)(sA + (size_t)(h*4096 + mrow*32 + kc)) = *(const uint4*)a8;
      }
    }
    __syncthreads();
#pragma unroll
    for (int h = 0; h < 2; ++h){
      short8 av[4], bv[4];
#pragma unroll
      for (int i=0;i<4;i++)
        av[i] = *(const short8*)(sA + h*4096 + (size_t)(wm*64 + i*16 + (lane&15))*32 + (lane>>4)*8);
#pragma unroll
      for (int j=0;j<4;j++)
        bv[j] = *(const short8*)(sB + h*4096 + (size_t)(wn*64 + j*16 + (lane&15))*32 + (lane>>4)*8);
#pragma unroll
      for (int i=0;i<4;i++)
#pragma unroll
        for (int j=0;j<4;j++)
          acc[i][j] = __builtin_amdgcn_mfma_f32_16x16x32_bf16(av[i], bv[j], acc[i][j], 0, 0, 0);
    }
  }
  epilogue_f32(acc, row0, col0, tid, HIDN, Out);
}

// ---------------- pass 1 (MFMA): Esum[k], Ut[v][k] = sum_s V[s][v] e[s][k]
// 512 thr, 8 waves (wm: 32-row v-band; wn: 64-col k-band).
__global__ __launch_bounds__(512, 2) void attn_pass1(
    const unsigned short* __restrict__ Kb, const unsigned short* __restrict__ Vb,
    unsigned short* __restrict__ U, float* __restrict__ Esum)
{
  __shared__ unsigned short Vt[128*LDSP], Et[128*LDSP];   // ~70 KB
  __shared__ float seg_part[4*128];
  int tid = threadIdx.x;
  const int lane = tid & 63, quad = lane >> 4;
  const int w = tid >> 6, wm = w & 3, wn = w >> 2;
  const int Rb = wm*32, Cb = wn*64;
  int bh = blockIdx.x >> 4, ch = blockIdx.x & 15;
  int b = bh >> 3, h = bh & 7;
  size_t rowbase = (size_t)(b*T_SEQ + ch*128)*HIDN + h*128;

#pragma unroll
  for (int i=0;i<4;i++){                   // transpose-stage V and e=exp(K)
    int u = tid + i*512; int t = u >> 4, kc = (u & 15)*8;
    unsigned short tmp[8];
    *(uint4*)tmp = *(const uint4*)&Vb[rowbase + (size_t)t*HIDN + kc];
#pragma unroll
    for (int j=0;j<8;j++) Vt[(kc+j)*LDSP + t] = tmp[j];
    float kv[8]; up8(&Kb[rowbase + (size_t)t*HIDN + kc], kv);
#pragma unroll
    for (int j=0;j<8;j++) Et[(kc+j)*LDSP + t] = f2bu(__expf(kv[j]));
  }
  __syncthreads();

  { // Esum[k] = row sums of Et
    int seg = tid >> 7, k = tid & 127;
    float s = 0.f;
    for (int c = seg*32; c < seg*32+32; ++c) s += bu2f(Et[k*LDSP + c]);
    seg_part[seg*128 + k] = s;
  }
  __syncthreads();
  if (tid < 128)
    Esum[(size_t)blockIdx.x*128 + tid] =
        seg_part[tid] + seg_part[128+tid] + seg_part[256+tid] + seg_part[384+tid];

  // Ut = Vt @ Et^T (contraction over s)
  f32x4 acc[2][4] = {};
  short8 av[2], bv[4];
#pragma unroll
  for (int s0=0; s0<128; s0+=32){
#pragma unroll
    for (int i=0;i<2;i++)
      av[i] = *(const short8*)(Vt + (Rb + i*16 + (lane&15))*LDSP + s0 + quad*8);
#pragma unroll
    for (int j=0;j<4;j++)
      bv[j] = *(const short8*)(Et + (Cb + j*16 + (lane&15))*LDSP + s0 + quad*8);
#pragma unroll
    for (int i=0;i<2;i++)
#pragma unroll
      for (int j=0;j<4;j++)
        acc[i][j] = __builtin_amdgcn_mfma_f32_16x16x32_bf16(av[i], bv[j], acc[i][j], 0,0,0);
  }
  __syncthreads();                         // all Et/Vt reads done

  // stage C (bf16) into Et region, coalesced copy-out
#pragma unroll
  for (int i=0;i<2;i++)
#pragma unroll
    for (int j=0;j<4;j++){
      int k = Cb + j*16 + (lane&15);
#pragma unroll
      for (int r=0;r<4;r++){
        int v = Rb + i*16 + quad*4 + r;
        Et[v*LDSP + k] = f2bu(acc[i][j][r]);
      }
    }
  __syncthreads();
  unsigned short* Ub = U + (size_t)blockIdx.x*16384;
#pragma unroll
  for (int i=0;i<4;i++){
    int u = tid + i*512; int v = u >> 4, kc = (u & 15)*8;
    *(uint4*)&Ub[v*128 + kc] = *(const uint4*)&Et[v*LDSP + kc];
  }
}

// ---------------- pass 2: exclusive prefix over chunks (in place) ----------
__global__ __launch_bounds__(256) void attn_pass2(
    unsigned short* __restrict__ U, float* __restrict__ Esum)
{
  int bh = blockIdx.x >> 4, sl = blockIdx.x & 15;
  int p = sl*1024 + threadIdx.x*4;
  float r0=0.f, r1=0.f, r2=0.f, r3=0.f;
  for (int c=0;c<16;c++){
    ushort4* ptr = (ushort4*)&U[(size_t)(bh*16 + c)*16384 + p];
    ushort4 t = *ptr;
    ushort4 w;
    w.x=f2bu(r0); w.y=f2bu(r1); w.z=f2bu(r2); w.w=f2bu(r3);
    *ptr = w;
    r0 += bu2f(t.x); r1 += bu2f(t.y); r2 += bu2f(t.z); r3 += bu2f(t.w);
  }
  if (sl == 0 && threadIdx.x < 128){
    float r = 0.f;
    for (int c=0;c<16;c++){
      float* q = &Esum[(size_t)(bh*16 + c)*128 + threadIdx.x];
      float t = *q; *q = r; r += t;
    }
  }
}

// ---------------- pass 3 (MFMA): o = qn@Cprev + causal(qn@e^T)@V + SumSq --
__global__ __launch_bounds__(512, 2) void attn_pass3(
    const unsigned short* __restrict__ Kb, const unsigned short* __restrict__ Qb,
    const unsigned short* __restrict__ Vb, const unsigned short* __restrict__ U,
    const float* __restrict__ Esum, unsigned short* __restrict__ Oatt,
    float* __restrict__ SumSq)
{
  __shared__ unsigned short smem[3*128*LDSP];     // 102 KB
  __shared__ float seg_part[4*128];
  unsigned short* bufA = smem;
  unsigned short* bufB = smem + 128*LDSP;
  unsigned short* bufC = smem + 2*128*LDSP;

  int tid = threadIdx.x;
  const int lane = tid & 63, quad = lane >> 4;
  const int w = tid >> 6, wm = w & 3, wn = w >> 2;
  const int Rb = wm*32, Cb = wn*64;
  int bh = blockIdx.x >> 4, ch = blockIdx.x & 15;
  int b = bh >> 3, h = bh & 7;
  size_t rowbase = (size_t)(b*T_SEQ + ch*128)*HIDN + h*128;

  // ---- stage Q, e=exp(K), Ut ----
#pragma unroll
  for (int i=0;i<4;i++){
    int u = tid + i*512; int t = u >> 4, kc = (u & 15)*8;
    *(uint4*)&bufA[t*LDSP + kc] = *(const uint4*)&Qb[rowbase + (size_t)t*HIDN + kc];
    float kv[8]; up8(&Kb[rowbase + (size_t)t*HIDN + kc], kv);
    ushort4 a, c;
    a.x=f2bu(__expf(kv[0])); a.y=f2bu(__expf(kv[1]));
    a.z=f2bu(__expf(kv[2])); a.w=f2bu(__expf(kv[3]));
    c.x=f2bu(__expf(kv[4])); c.y=f2bu(__expf(kv[5]));
    c.z=f2bu(__expf(kv[6])); c.w=f2bu(__expf(kv[7]));
    *(ushort4*)&bufB[t*LDSP + kc    ] = a;
    *(ushort4*)&bufB[t*LDSP + kc + 4] = c;
    *(uint4*)&bufC[t*LDSP + kc] =
        *(const uint4*)&U[(size_t)blockIdx.x*16384 + (size_t)t*128 + kc];
  }
  __syncthreads();

  // ---- qn = q*SCALE/E_t ; 4-way segmented inclusive cumsum over t ----
  {
    int col = tid & 127, seg = tid >> 7;
    float psum = 0.f;
    for (int s = seg*32; s < seg*32+32; ++s) psum += bu2f(bufB[s*LDSP + col]);
    seg_part[seg*128 + col] = psum;
    __syncthreads();
    float run = Esum[(size_t)blockIdx.x*128 + col];
    for (int ss=0; ss<4; ++ss) if (ss < seg) run += seg_part[ss*128 + col];
    for (int s = seg*32; s < seg*32+32; ++s){
      run += bu2f(bufB[s*LDSP + col]);
      float q = bu2f(bufA[s*LDSP + col]);
      bufA[s*LDSP + col] = f2bu(q * SCALE * __builtin_amdgcn_rcpf(run));
    }
  }
  __syncthreads();

  // ---- inter: O = QN @ Ut^T ; scores: P = QN @ E^T ----
  f32x4 accO[2][4] = {}, accP[2][4] = {};
  short8 av[2], bv[4];
#pragma unroll
  for (int k0=0; k0<128; k0+=32){
#pragma unroll
    for (int i=0;i<2;i++)
      av[i] = *(const short8*)(bufA + (Rb + i*16 + (lane&15))*LDSP + k0 + quad*8);
#pragma unroll
    for (int j=0;j<4;j++)
      bv[j] = *(const short8*)(bufC + (Cb + j*16 + (lane&15))*LDSP + k0 + quad*8);
#pragma unroll
    for (int i=0;i<2;i++)
#pragma unroll
      for (int j=0;j<4;j++)
        accO[i][j] = __builtin_amdgcn_mfma_f32_16x16x32_bf16(av[i], bv[j], accO[i][j], 0,0,0);
#pragma unroll
    for (int j=0;j<4;j++)
      bv[j] = *(const short8*)(bufB + (Cb + j*16 + (lane&15))*LDSP + k0 + quad*8);
#pragma unroll
    for (int i=0;i<2;i++)
#pragma unroll
      for (int j=0;j<4;j++)
        accP[i][j] = __builtin_amdgcn_mfma_f32_16x16x32_bf16(av[i], bv[j], accP[i][j], 0,0,0);
  }
  __syncthreads();

  // ---- masked P -> bufA [t][s] ; V^T -> bufB [v][s] ----
#pragma unroll
  for (int i=0;i<2;i++){
#pragma unroll
    for (int j=0;j<4;j++){
      int s = Cb + j*16 + (lane&15);
#pragma unroll
      for (int r=0;r<4;r++){
        int t = Rb + i*16 + quad*4 + r;
        bufA[t*LDSP + s] = f2bu(s <= t ? accP[i][j][r] : 0.f);
      }
    }
  }
#pragma unroll
  for (int i=0;i<4;i++){
    int u = tid + i*512; int t = u >> 4, kc = (u & 15)*8;
    unsigned short tmp[8];
    *(uint4*)tmp = *(const uint4*)&Vb[rowbase + (size_t)t*HIDN + kc];
#pragma unroll
    for (int j=0;j<8;j++) bufB[(kc+j)*LDSP + t] = tmp[j];
  }
  __syncthreads();

  // ---- intra: O += P @ Vt^T ----
#pragma unroll
  for (int k0=0; k0<128; k0+=32){
#pragma unroll
    for (int i=0;i<2;i++)
      av[i] = *(const short8*)(bufA + (Rb + i*16 + (lane&15))*LDSP + k0 + quad*8);
#pragma unroll
    for (int j=0;j<4;j++)
      bv[j] = *(const short8*)(bufB + (Cb + j*16 + (lane&15))*LDSP + k0 + quad*8);
#pragma unroll
    for (int i=0;i<2;i++)
#pragma unroll
      for (int j=0;j<4;j++)
        accO[i][j] = __builtin_amdgcn_mfma_f32_16x16x32_bf16(av[i], bv[j], accO[i][j], 0,0,0);
  }
  __syncthreads();

  // ---- O -> bufC (bf16) ----
#pragma unroll
  for (int i=0;i<2;i++){
#pragma unroll
    for (int j=0;j<4;j++){
      int v = Cb + j*16 + (lane&15);
#pragma unroll
      for (int r=0;r<4;r++){
        int t = Rb + i*16 + quad*4 + r;
        bufC[t*LDSP + v] = f2bu(accO[i][j][r]);
      }
    }
  }
  __syncthreads();

  // ---- per-row sum of squares (this head's 128 cols) ----
  {
    int seg = tid >> 7, row = tid & 127;
    float s = 0.f;
    for (int c = seg*32; c < seg*32+32; ++c){
      float x = bu2f(bufC[row*LDSP + c]); s += x*x;
    }
    seg_part[seg*128 + row] = s;
  }
  // ---- coalesced O write ----
#pragma unroll
  for (int i=0;i<4;i++){
    int u = tid + i*512; int t = u >> 4, kc = (u & 15)*8;
    *(uint4*)&Oatt[rowbase + (size_t)t*HIDN + kc] = *(const uint4*)&bufC[t*LDSP + kc];
  }
  __syncthreads();
  if (tid < 128){
    float s = seg_part[tid] + seg_part[128+tid] + seg_part[256+tid] + seg_part[384+tid];
    atomicAdd(&SumSq[(size_t)b*T_SEQ + ch*128 + tid], s);
  }
}

// ---------------- launch ----------------
extern "C" void kernel_launch(void* const* d_in, const int* in_sizes, int n_in,
                              void* d_out, int out_size, void* d_ws, size_t ws_size,
                              hipStream_t stream) {
  unsigned short* wsS = (unsigned short*)d_ws;     // ~69 MiB used

  unsigned short* Xc   = wsS;              // 4,194,304
  unsigned short* Wqc  = wsS + 4194304;
  unsigned short* Wkc  = wsS + 5242880;
  unsigned short* Wvc  = wsS + 6291456;
  unsigned short* Woc  = wsS + 7340032;
  unsigned short* Wg1c = wsS + 8388608;
  unsigned short* Wg2c = wsS + 8519680;
  unsigned short* gnwc = wsS + 8650752;
  unsigned short* Qb   = wsS + 8651776;
  unsigned short* Kb   = wsS + 12846080;
  unsigned short* Vb   = wsS + 17040384;
  unsigned short* G1b  = wsS + 21234688;
  unsigned short* Gt   = wsS + 21758976;
  unsigned short* Ub   = wsS + 25953280;
  unsigned short* Oattb= wsS + 30147584;
  float*          Esum = (float*)(wsS + 34341888);  // 32,768 floats
  float*          SumSq= (float*)(wsS + 34407424);  //  4,096 floats

  convert_all<<<8453, 256, 0, stream>>>(
      (const float*)d_in[0], (const float*)d_in[1], (const float*)d_in[2],
      (const float*)d_in[3], (const float*)d_in[4], (const float*)d_in[5],
      (const float*)d_in[6], (const float*)d_in[7], wsS, SumSq);

  proj_kernel<<<dim3(32,25), 256, 0, stream>>>(Xc, Wqc, Wkc, Wvc, Wg1c, Qb, Kb, Vb, G1b);
  gemm_bt   <<<dim3(32,8),  256, 0, stream>>>(G1b, Wg2c, 128, HIDN, 1, Gt);
  attn_pass1<<<256, 512, 0, stream>>>(Kb, Vb, Ub, Esum);
  attn_pass2<<<256, 256, 0, stream>>>(Ub, Esum);
  attn_pass3<<<256, 512, 0, stream>>>(Kb, Qb, Vb, Ub, Esum, Oattb, SumSq);
  out_gemm  <<<dim3(32,8),  256, 0, stream>>>(Oattb, Gt, gnwc, SumSq, Woc,
                                              (float*)d_out);
}

// Round 8
// 211.746 us; speedup vs baseline: 1.0561x; 1.0561x over previous
//
#include <hip/hip_runtime.h>
#include <hip/hip_bf16.h>
#include <stdint.h>

// LightNet attention fwd. B=2, T=2048, HID=1024, H=8, DK=DV=128, LR=128.
// Contract (R1-R4): inputs fp32, output fp32.
//
// o_t[v] = scale * sum_k (q_t[k]/E_t[k]) * sum_{s<=t} e_s[k] v_s[v],
// e=exp(k), E=cumsum(e). Chunked Tc=128: pass1 (MFMA) Esum + Ut=(e^T V)^T;
// pass2 exclusive chunk prefix; pass3 (MFMA) intra(causal)+inter + atomic
// row sum-of-squares; norm_gate2 elementwise (no reduction); final GEMM
// fully async (R7 post-mortem: fusing norm into out_gemm's A-staging broke
// the async pipeline and cost ~15us — reverted).
// proj stores e=exp(k) directly (act=2 epilogue) so pass1/pass3 skip expf.
// GEMMs: bf16 MFMA 128x128 tile, BK=64 (2x32 sub-tiles per barrier pair),
// global_load_lds width-16 staging, LDS-staged coalesced bf16 epilogue.

typedef short short8 __attribute__((ext_vector_type(8)));
typedef float f32x4 __attribute__((ext_vector_type(4)));

#define T_SEQ 2048
#define HIDN  1024
#define SCALE 0.08838834764831845f   // 128^-0.5
#define LDSP  136                    // padded LDS row stride (shorts)

// ---------------- bf16 bit helpers ----------------
__device__ __forceinline__ float blo(unsigned int u){
  union{unsigned int i; float f;} v; v.i = u << 16; return v.f;
}
__device__ __forceinline__ float bhi(unsigned int u){
  union{unsigned int i; float f;} v; v.i = u & 0xffff0000u; return v.f;
}
__device__ __forceinline__ float bu2f(unsigned short u){
  union{unsigned int i; float f;} v; v.i = ((unsigned int)u) << 16; return v.f;
}
__device__ __forceinline__ unsigned short f2bu(float f){
  union{float f; unsigned int i;} v; v.f = f;
  unsigned int x = v.i;
  x += 0x7fffu + ((x >> 16) & 1u);     // RNE
  return (unsigned short)(x >> 16);
}
__device__ __forceinline__ void up8(const unsigned short* p, float* f){
  uint4 v = *(const uint4*)p;
  f[0]=blo(v.x); f[1]=bhi(v.x); f[2]=blo(v.y); f[3]=bhi(v.y);
  f[4]=blo(v.z); f[5]=bhi(v.z); f[6]=blo(v.w); f[7]=bhi(v.w);
}
__device__ __forceinline__ void async16(const void* g, void* l){
  __builtin_amdgcn_global_load_lds(
      (const __attribute__((address_space(1))) unsigned int*)g,
      (__attribute__((address_space(3))) unsigned int*)l, 16, 0, 0);
}

// ---------------- fused input cast + SumSq zeroing ------------------------
__global__ __launch_bounds__(256) void convert_all(
    const float* __restrict__ X,  const float* __restrict__ Wq,
    const float* __restrict__ Wk, const float* __restrict__ Wv,
    const float* __restrict__ Wg1,const float* __restrict__ Wg2,
    const float* __restrict__ gnw,const float* __restrict__ Wo,
    unsigned short* __restrict__ base, float* __restrict__ SumSq)
{
  int q = blockIdx.x * 256 + threadIdx.x;
  const float* src; unsigned short* dst; int rel = q;
  if (rel < 1048576)            { src = X;   dst = base;            }
  else if ((rel -= 1048576) < 262144) { src = Wq;  dst = base + 4194304; }
  else if ((rel -=  262144) < 262144) { src = Wk;  dst = base + 5242880; }
  else if ((rel -=  262144) < 262144) { src = Wv;  dst = base + 6291456; }
  else if ((rel -=  262144) < 262144) { src = Wo;  dst = base + 7340032; }
  else if ((rel -=  262144) <  32768) { src = Wg1; dst = base + 8388608; }
  else if ((rel -=   32768) <  32768) { src = Wg2; dst = base + 8519680; }
  else if ((rel -=   32768) <    256) { src = gnw; dst = base + 8650752; }
  else { rel -= 256;                              // zero SumSq (4096 floats)
    ((float4*)SumSq)[rel] = make_float4(0.f,0.f,0.f,0.f); return; }
  float4 v = ((const float4*)src)[rel];
  ushort4 o; o.x=f2bu(v.x); o.y=f2bu(v.y); o.z=f2bu(v.z); o.w=f2bu(v.w);
  ((ushort4*)dst)[rel] = o;
}

// ---------------- MFMA GEMM core: C(128x128)=A@B^T, BK=64 (2x32) ---------
__device__ __forceinline__ void gemm_core(
    const unsigned short* __restrict__ A, const unsigned short* __restrict__ B,
    int K, int row0, int col0,
    unsigned short* sA, unsigned short* sB, f32x4 acc[4][4], int tid)
{
  const int lane = tid & 63;
  const int wm = (tid >> 6) & 1, wn = tid >> 7;
  const int wb = tid & 192;                // wave-uniform chunk base
  for (int k0 = 0; k0 < K; k0 += 64){
    __syncthreads();                       // prev iter's LDS reads done
#pragma unroll
    for (int h = 0; h < 2; ++h){
#pragma unroll
      for (int r = 0; r < 2; ++r){
        int idx  = r*256 + tid;            // 512 chunks of 16B per sub-tile
        int mrow = idx >> 2, kc = (idx & 3) * 8;
        async16(A + (size_t)(row0 + mrow)*K + k0 + h*32 + kc,
                sA + (size_t)(h*512 + r*256 + wb)*8);
        async16(B + (size_t)(col0 + mrow)*K + k0 + h*32 + kc,
                sB + (size_t)(h*512 + r*256 + wb)*8);
      }
    }
    __syncthreads();                       // drains vmcnt before barrier
#pragma unroll
    for (int h = 0; h < 2; ++h){
      short8 av[4], bv[4];
#pragma unroll
      for (int i=0;i<4;i++)
        av[i] = *(const short8*)(sA + h*4096 + (size_t)(wm*64 + i*16 + (lane&15))*32 + (lane>>4)*8);
#pragma unroll
      for (int j=0;j<4;j++)
        bv[j] = *(const short8*)(sB + h*4096 + (size_t)(wn*64 + j*16 + (lane&15))*32 + (lane>>4)*8);
#pragma unroll
      for (int i=0;i<4;i++)
#pragma unroll
        for (int j=0;j<4;j++)
          acc[i][j] = __builtin_amdgcn_mfma_f32_16x16x32_bf16(av[i], bv[j], acc[i][j], 0, 0, 0);
    }
  }
}

// bf16 epilogue via LDS. act: 0 none, 1 silu/swish, 2 exp.
__device__ __forceinline__ void epilogue_lds(
    f32x4 acc[4][4], int row0, int col0, int tid, int ldc, int act,
    unsigned short* __restrict__ Cb, unsigned short* sC)
{
  const int lane = tid & 63;
  const int wm = (tid >> 6) & 1, wn = tid >> 7;
#pragma unroll
  for (int p=0;p<4;p++){
    __syncthreads();
    if (wm == (p>>1)){
#pragma unroll
      for (int ii=0; ii<2; ii++){
        int i = (p&1)*2 + ii;
        int lr = i*16 + ((lane>>4)<<2) - (p&1)*32;   // local row in [0,32)
#pragma unroll
        for (int j=0;j<4;j++){
          int col = wn*64 + j*16 + (lane&15);
#pragma unroll
          for (int r=0;r<4;r++){
            float v = acc[i][j][r];
            if (act == 1) v = v / (1.f + __expf(-v));
            else if (act == 2) v = __expf(v);
            sC[(lr+r)*128 + col] = f2bu(v);
          }
        }
      }
    }
    __syncthreads();
#pragma unroll
    for (int c = tid; c < 512; c += 256){  // 32 rows x 256B
      int rr = c >> 4, off = (c & 15)*8;
      *(uint4*)&Cb[(size_t)(row0 + p*32 + rr)*ldc + col0 + off] =
          *(const uint4*)&sC[rr*128 + off];
    }
  }
}

// fp32 direct epilogue (64B full-line segments).
__device__ __forceinline__ void epilogue_f32(
    f32x4 acc[4][4], int row0, int col0, int tid, int ldc,
    float* __restrict__ Cf)
{
  const int lane = tid & 63;
  const int wm = (tid >> 6) & 1, wn = tid >> 7;
#pragma unroll
  for (int i=0;i<4;i++){
    int rbase = row0 + wm*64 + i*16 + ((lane>>4)<<2);
#pragma unroll
    for (int j=0;j<4;j++){
      int col = col0 + wn*64 + j*16 + (lane&15);
#pragma unroll
      for (int r=0;r<4;r++)
        Cf[(size_t)(rbase + r)*ldc + col] = acc[i][j][r];
    }
  }
}

// Fused QKV+G1 projection. grid (32, 25): y<8 Q(silu), <16 K->e (exp!),
// <24 V, ==24 G1.
__global__ __launch_bounds__(256, 2) void proj_kernel(
    const unsigned short* __restrict__ X,
    const unsigned short* __restrict__ Wq, const unsigned short* __restrict__ Wk,
    const unsigned short* __restrict__ Wv, const unsigned short* __restrict__ Wg1,
    unsigned short* __restrict__ Qb, unsigned short* __restrict__ Eb,
    unsigned short* __restrict__ Vb, unsigned short* __restrict__ G1b)
{
  __shared__ unsigned short sA[128*64], sB[128*64];
  int tid = threadIdx.x;
  int which = blockIdx.y >> 3;
  const unsigned short* Bp = (which==0)?Wq:(which==1)?Wk:(which==2)?Wv:Wg1;
  int row0 = blockIdx.x * 128;
  int col0 = (which==3) ? 0 : (blockIdx.y & 7) * 128;
  f32x4 acc[4][4] = {};
  gemm_core(X, Bp, HIDN, row0, col0, sA, sB, acc, tid);
  if      (which==0) epilogue_lds(acc,row0,col0,tid,HIDN,1,Qb, sA);
  else if (which==1) epilogue_lds(acc,row0,col0,tid,HIDN,2,Eb, sA);  // e=exp(k)
  else if (which==2) epilogue_lds(acc,row0,col0,tid,HIDN,0,Vb, sA);
  else               epilogue_lds(acc,row0,col0,tid,128 ,0,G1b,sA);
}

// Generic A@B^T. Cb nonnull -> bf16 LDS epilogue (act); else fp32 direct.
__global__ __launch_bounds__(256, 2) void gemm_bt(
    const unsigned short* __restrict__ A, const unsigned short* __restrict__ B,
    int K, int ldc, int act, float* __restrict__ Cf,
    unsigned short* __restrict__ Cb)
{
  __shared__ unsigned short sA[128*64], sB[128*64];
  int tid = threadIdx.x;
  int row0 = blockIdx.x * 128, col0 = blockIdx.y * 128;
  f32x4 acc[4][4] = {};
  gemm_core(A, B, K, row0, col0, sA, sB, acc, tid);
  if (Cb) epilogue_lds(acc, row0, col0, tid, ldc, act, Cb, sA);
  else    epilogue_f32(acc, row0, col0, tid, ldc, Cf);
}

// ---------------- pass 1 (MFMA): Esum[k], Ut[v][k] = sum_s V[s][v] e[s][k]
__global__ __launch_bounds__(512, 2) void attn_pass1(
    const unsigned short* __restrict__ Eb, const unsigned short* __restrict__ Vb,
    unsigned short* __restrict__ U, float* __restrict__ Esum)
{
  __shared__ unsigned short Vt[128*LDSP], Et[128*LDSP];   // ~70 KB
  __shared__ float seg_part[4*128];
  int tid = threadIdx.x;
  const int lane = tid & 63, quad = lane >> 4;
  const int w = tid >> 6, wm = w & 3, wn = w >> 2;
  const int Rb = wm*32, Cb = wn*64;
  int bh = blockIdx.x >> 4, ch = blockIdx.x & 15;
  int b = bh >> 3, h = bh & 7;
  size_t rowbase = (size_t)(b*T_SEQ + ch*128)*HIDN + h*128;

#pragma unroll
  for (int i=0;i<4;i++){                   // transpose-stage V and e
    int u = tid + i*512; int t = u >> 4, kc = (u & 15)*8;
    unsigned short tmp[8];
    *(uint4*)tmp = *(const uint4*)&Vb[rowbase + (size_t)t*HIDN + kc];
#pragma unroll
    for (int j=0;j<8;j++) Vt[(kc+j)*LDSP + t] = tmp[j];
    *(uint4*)tmp = *(const uint4*)&Eb[rowbase + (size_t)t*HIDN + kc];
#pragma unroll
    for (int j=0;j<8;j++) Et[(kc+j)*LDSP + t] = tmp[j];
  }
  __syncthreads();

  { // Esum[k] = row sums of Et
    int seg = tid >> 7, k = tid & 127;
    float s = 0.f;
    for (int c = seg*32; c < seg*32+32; ++c) s += bu2f(Et[k*LDSP + c]);
    seg_part[seg*128 + k] = s;
  }
  __syncthreads();
  if (tid < 128)
    Esum[(size_t)blockIdx.x*128 + tid] =
        seg_part[tid] + seg_part[128+tid] + seg_part[256+tid] + seg_part[384+tid];

  // Ut = Vt @ Et^T (contraction over s)
  f32x4 acc[2][4] = {};
  short8 av[2], bv[4];
#pragma unroll
  for (int s0=0; s0<128; s0+=32){
#pragma unroll
    for (int i=0;i<2;i++)
      av[i] = *(const short8*)(Vt + (Rb + i*16 + (lane&15))*LDSP + s0 + quad*8);
#pragma unroll
    for (int j=0;j<4;j++)
      bv[j] = *(const short8*)(Et + (Cb + j*16 + (lane&15))*LDSP + s0 + quad*8);
#pragma unroll
    for (int i=0;i<2;i++)
#pragma unroll
      for (int j=0;j<4;j++)
        acc[i][j] = __builtin_amdgcn_mfma_f32_16x16x32_bf16(av[i], bv[j], acc[i][j], 0,0,0);
  }
  __syncthreads();                         // all Et/Vt reads done

  // stage C (bf16) into Et region, coalesced copy-out
#pragma unroll
  for (int i=0;i<2;i++)
#pragma unroll
    for (int j=0;j<4;j++){
      int k = Cb + j*16 + (lane&15);
#pragma unroll
      for (int r=0;r<4;r++){
        int v = Rb + i*16 + quad*4 + r;
        Et[v*LDSP + k] = f2bu(acc[i][j][r]);
      }
    }
  __syncthreads();
  unsigned short* Ub = U + (size_t)blockIdx.x*16384;
#pragma unroll
  for (int i=0;i<4;i++){
    int u = tid + i*512; int v = u >> 4, kc = (u & 15)*8;
    *(uint4*)&Ub[v*128 + kc] = *(const uint4*)&Et[v*LDSP + kc];
  }
}

// ---------------- pass 2: exclusive prefix over chunks (in place) ----------
__global__ __launch_bounds__(256) void attn_pass2(
    unsigned short* __restrict__ U, float* __restrict__ Esum)
{
  int bh = blockIdx.x >> 4, sl = blockIdx.x & 15;
  int p = sl*1024 + threadIdx.x*4;
  float r0=0.f, r1=0.f, r2=0.f, r3=0.f;
  for (int c=0;c<16;c++){
    ushort4* ptr = (ushort4*)&U[(size_t)(bh*16 + c)*16384 + p];
    ushort4 t = *ptr;
    ushort4 w;
    w.x=f2bu(r0); w.y=f2bu(r1); w.z=f2bu(r2); w.w=f2bu(r3);
    *ptr = w;
    r0 += bu2f(t.x); r1 += bu2f(t.y); r2 += bu2f(t.z); r3 += bu2f(t.w);
  }
  if (sl == 0 && threadIdx.x < 128){
    float r = 0.f;
    for (int c=0;c<16;c++){
      float* q = &Esum[(size_t)(bh*16 + c)*128 + threadIdx.x];
      float t = *q; *q = r; r += t;
    }
  }
}

// ---------------- pass 3 (MFMA): o = qn@Cprev + causal(qn@e^T)@V + SumSq --
__global__ __launch_bounds__(512, 2) void attn_pass3(
    const unsigned short* __restrict__ Eb, const unsigned short* __restrict__ Qb,
    const unsigned short* __restrict__ Vb, const unsigned short* __restrict__ U,
    const float* __restrict__ Esum, unsigned short* __restrict__ Oatt,
    float* __restrict__ SumSq)
{
  __shared__ unsigned short smem[3*128*LDSP];     // 102 KB
  __shared__ float seg_part[4*128];
  unsigned short* bufA = smem;
  unsigned short* bufB = smem + 128*LDSP;
  unsigned short* bufC = smem + 2*128*LDSP;

  int tid = threadIdx.x;
  const int lane = tid & 63, quad = lane >> 4;
  const int w = tid >> 6, wm = w & 3, wn = w >> 2;
  const int Rb = wm*32, Cb = wn*64;
  int bh = blockIdx.x >> 4, ch = blockIdx.x & 15;
  int b = bh >> 3, h = bh & 7;
  size_t rowbase = (size_t)(b*T_SEQ + ch*128)*HIDN + h*128;

  // ---- stage Q, e, Ut ----
#pragma unroll
  for (int i=0;i<4;i++){
    int u = tid + i*512; int t = u >> 4, kc = (u & 15)*8;
    *(uint4*)&bufA[t*LDSP + kc] = *(const uint4*)&Qb[rowbase + (size_t)t*HIDN + kc];
    *(uint4*)&bufB[t*LDSP + kc] = *(const uint4*)&Eb[rowbase + (size_t)t*HIDN + kc];
    *(uint4*)&bufC[t*LDSP + kc] =
        *(const uint4*)&U[(size_t)blockIdx.x*16384 + (size_t)t*128 + kc];
  }
  __syncthreads();

  // ---- qn = q*SCALE/E_t ; 4-way segmented inclusive cumsum over t ----
  {
    int col = tid & 127, seg = tid >> 7;
    float psum = 0.f;
    for (int s = seg*32; s < seg*32+32; ++s) psum += bu2f(bufB[s*LDSP + col]);
    seg_part[seg*128 + col] = psum;
    __syncthreads();
    float run = Esum[(size_t)blockIdx.x*128 + col];
    for (int ss=0; ss<4; ++ss) if (ss < seg) run += seg_part[ss*128 + col];
    for (int s = seg*32; s < seg*32+32; ++s){
      run += bu2f(bufB[s*LDSP + col]);
      float q = bu2f(bufA[s*LDSP + col]);
      bufA[s*LDSP + col] = f2bu(q * SCALE * __builtin_amdgcn_rcpf(run));
    }
  }
  __syncthreads();

  // ---- inter: O = QN @ Ut^T ; scores: P = QN @ E^T ----
  f32x4 accO[2][4] = {}, accP[2][4] = {};
  short8 av[2], bv[4];
#pragma unroll
  for (int k0=0; k0<128; k0+=32){
#pragma unroll
    for (int i=0;i<2;i++)
      av[i] = *(const short8*)(bufA + (Rb + i*16 + (lane&15))*LDSP + k0 + quad*8);
#pragma unroll
    for (int j=0;j<4;j++)
      bv[j] = *(const short8*)(bufC + (Cb + j*16 + (lane&15))*LDSP + k0 + quad*8);
#pragma unroll
    for (int i=0;i<2;i++)
#pragma unroll
      for (int j=0;j<4;j++)
        accO[i][j] = __builtin_amdgcn_mfma_f32_16x16x32_bf16(av[i], bv[j], accO[i][j], 0,0,0);
#pragma unroll
    for (int j=0;j<4;j++)
      bv[j] = *(const short8*)(bufB + (Cb + j*16 + (lane&15))*LDSP + k0 + quad*8);
#pragma unroll
    for (int i=0;i<2;i++)
#pragma unroll
      for (int j=0;j<4;j++)
        accP[i][j] = __builtin_amdgcn_mfma_f32_16x16x32_bf16(av[i], bv[j], accP[i][j], 0,0,0);
  }
  __syncthreads();

  // ---- masked P -> bufA [t][s] ; V^T -> bufB [v][s] ----
#pragma unroll
  for (int i=0;i<2;i++){
#pragma unroll
    for (int j=0;j<4;j++){
      int s = Cb + j*16 + (lane&15);
#pragma unroll
      for (int r=0;r<4;r++){
        int t = Rb + i*16 + quad*4 + r;
        bufA[t*LDSP + s] = f2bu(s <= t ? accP[i][j][r] : 0.f);
      }
    }
  }
#pragma unroll
  for (int i=0;i<4;i++){
    int u = tid + i*512; int t = u >> 4, kc = (u & 15)*8;
    unsigned short tmp[8];
    *(uint4*)tmp = *(const uint4*)&Vb[rowbase + (size_t)t*HIDN + kc];
#pragma unroll
    for (int j=0;j<8;j++) bufB[(kc+j)*LDSP + t] = tmp[j];
  }
  __syncthreads();

  // ---- intra: O += P @ Vt^T ----
#pragma unroll
  for (int k0=0; k0<128; k0+=32){
#pragma unroll
    for (int i=0;i<2;i++)
      av[i] = *(const short8*)(bufA + (Rb + i*16 + (lane&15))*LDSP + k0 + quad*8);
#pragma unroll
    for (int j=0;j<4;j++)
      bv[j] = *(const short8*)(bufB + (Cb + j*16 + (lane&15))*LDSP + k0 + quad*8);
#pragma unroll
    for (int i=0;i<2;i++)
#pragma unroll
      for (int j=0;j<4;j++)
        accO[i][j] = __builtin_amdgcn_mfma_f32_16x16x32_bf16(av[i], bv[j], accO[i][j], 0,0,0);
  }
  __syncthreads();

  // ---- O -> bufC (bf16) ----
#pragma unroll
  for (int i=0;i<2;i++){
#pragma unroll
    for (int j=0;j<4;j++){
      int v = Cb + j*16 + (lane&15);
#pragma unroll
      for (int r=0;r<4;r++){
        int t = Rb + i*16 + quad*4 + r;
        bufC[t*LDSP + v] = f2bu(accO[i][j][r]);
      }
    }
  }
  __syncthreads();

  // ---- per-row sum of squares (this head's 128 cols) ----
  {
    int seg = tid >> 7, row = tid & 127;
    float s = 0.f;
    for (int c = seg*32; c < seg*32+32; ++c){
      float x = bu2f(bufC[row*LDSP + c]); s += x*x;
    }
    seg_part[seg*128 + row] = s;
  }
  // ---- coalesced O write ----
#pragma unroll
  for (int i=0;i<4;i++){
    int u = tid + i*512; int t = u >> 4, kc = (u & 15)*8;
    *(uint4*)&Oatt[rowbase + (size_t)t*HIDN + kc] = *(const uint4*)&bufC[t*LDSP + kc];
  }
  __syncthreads();
  if (tid < 128){
    float s = seg_part[tid] + seg_part[128+tid] + seg_part[256+tid] + seg_part[384+tid];
    atomicAdd(&SumSq[(size_t)b*T_SEQ + ch*128 + tid], s);
  }
}

// ---- norm_gate2: elementwise RMSNorm(SumSq)*gnw*swish-gate -> bf16 -------
__global__ __launch_bounds__(256) void norm_gate2(
    const unsigned short* __restrict__ Oatt, const unsigned short* __restrict__ Gt,
    const unsigned short* __restrict__ gnw, const float* __restrict__ SumSq,
    unsigned short* __restrict__ Onorm)
{
  int row = blockIdx.x, tid = threadIdx.x;
  float rstd = rsqrtf(SumSq[row] * (1.f/1024.f) + 1e-5f);
  ushort4 o4 = *(const ushort4*)&Oatt[(size_t)row*HIDN + tid*4];
  ushort4 g4 = *(const ushort4*)&Gt  [(size_t)row*HIDN + tid*4];
  ushort4 w4 = *(const ushort4*)&gnw[tid*4];
  ushort4 r4;
  r4.x = f2bu(bu2f(o4.x) * rstd * bu2f(w4.x) * bu2f(g4.x));
  r4.y = f2bu(bu2f(o4.y) * rstd * bu2f(w4.y) * bu2f(g4.y));
  r4.z = f2bu(bu2f(o4.z) * rstd * bu2f(w4.z) * bu2f(g4.z));
  r4.w = f2bu(bu2f(o4.w) * rstd * bu2f(w4.w) * bu2f(g4.w));
  *(ushort4*)&Onorm[(size_t)row*HIDN + tid*4] = r4;
}

// ---------------- launch ----------------
extern "C" void kernel_launch(void* const* d_in, const int* in_sizes, int n_in,
                              void* d_out, int out_size, void* d_ws, size_t ws_size,
                              hipStream_t stream) {
  unsigned short* wsS = (unsigned short*)d_ws;     // ~69 MiB used

  unsigned short* Xc   = wsS;              // 4,194,304
  unsigned short* Wqc  = wsS + 4194304;
  unsigned short* Wkc  = wsS + 5242880;
  unsigned short* Wvc  = wsS + 6291456;
  unsigned short* Woc  = wsS + 7340032;
  unsigned short* Wg1c = wsS + 8388608;
  unsigned short* Wg2c = wsS + 8519680;
  unsigned short* gnwc = wsS + 8650752;
  unsigned short* Qb   = wsS + 8651776;
  unsigned short* Eb   = wsS + 12846080;   // e = exp(k), bf16
  unsigned short* Vb   = wsS + 17040384;
  unsigned short* G1b  = wsS + 21234688;
  unsigned short* Gt   = wsS + 21758976;
  unsigned short* Ub   = wsS + 25953280;
  unsigned short* Oattb= wsS + 30147584;
  float*          Esum = (float*)(wsS + 34341888);  // 32,768 floats
  float*          SumSq= (float*)(wsS + 34407424);  //  4,096 floats
  unsigned short* Onorm = Qb;              // Q dead after pass3

  convert_all<<<8453, 256, 0, stream>>>(
      (const float*)d_in[0], (const float*)d_in[1], (const float*)d_in[2],
      (const float*)d_in[3], (const float*)d_in[4], (const float*)d_in[5],
      (const float*)d_in[6], (const float*)d_in[7], wsS, SumSq);

  proj_kernel<<<dim3(32,25), 256, 0, stream>>>(Xc, Wqc, Wkc, Wvc, Wg1c, Qb, Eb, Vb, G1b);
  gemm_bt   <<<dim3(32,8),  256, 0, stream>>>(G1b, Wg2c, 128, HIDN, 1, nullptr, Gt);
  attn_pass1<<<256, 512, 0, stream>>>(Eb, Vb, Ub, Esum);
  attn_pass2<<<256, 256, 0, stream>>>(Ub, Esum);
  attn_pass3<<<256, 512, 0, stream>>>(Eb, Qb, Vb, Ub, Esum, Oattb, SumSq);
  norm_gate2<<<4096, 256, 0, stream>>>(Oattb, Gt, gnwc, SumSq, Onorm);
  gemm_bt   <<<dim3(32,8),  256, 0, stream>>>(Onorm, Woc, HIDN, HIDN, 0,
                                              (float*)d_out, nullptr);
}

// Round 9
// 206.184 us; speedup vs baseline: 1.0845x; 1.0270x over previous
//
#include <hip/hip_runtime.h>
#include <hip/hip_bf16.h>
#include <stdint.h>

// LightNet attention fwd. B=2, T=2048, HID=1024, H=8, DK=DV=128, LR=128.
// Contract (R1-R4): inputs fp32, output fp32.
//
// o_t[v] = scale * sum_k (q_t[k]/E_t[k]) * sum_{s<=t} e_s[k] v_s[v],
// e=exp(k), E=cumsum(e). Chunked Tc=128: pass1 (MFMA) Esum + Ut=(e^T V)^T;
// pass2 exclusive chunk prefix; pass3 (MFMA) intra(causal)+inter + atomic
// row sum-of-squares; norm_gate2 elementwise; final GEMM fully async.
// R8->R9: GEMMs at __launch_bounds__(256,4) (occupancy 2->4 blocks/CU;
// R8 counters: Occ 18.5%, nothing saturated). pass3 reads Ut direct from
// global (no reuse -> LDS staging was overhead), LDS 102->68 KB, (512,4).
// GEMMs: bf16 MFMA 128x128 tile, BK=64 (2x32 sub-tiles per barrier pair),
// global_load_lds width-16 staging, LDS-staged coalesced bf16 epilogue.

typedef short short8 __attribute__((ext_vector_type(8)));
typedef float f32x4 __attribute__((ext_vector_type(4)));

#define T_SEQ 2048
#define HIDN  1024
#define SCALE 0.08838834764831845f   // 128^-0.5
#define LDSP  136                    // padded LDS row stride (shorts)

// ---------------- bf16 bit helpers ----------------
__device__ __forceinline__ float blo(unsigned int u){
  union{unsigned int i; float f;} v; v.i = u << 16; return v.f;
}
__device__ __forceinline__ float bhi(unsigned int u){
  union{unsigned int i; float f;} v; v.i = u & 0xffff0000u; return v.f;
}
__device__ __forceinline__ float bu2f(unsigned short u){
  union{unsigned int i; float f;} v; v.i = ((unsigned int)u) << 16; return v.f;
}
__device__ __forceinline__ unsigned short f2bu(float f){
  union{float f; unsigned int i;} v; v.f = f;
  unsigned int x = v.i;
  x += 0x7fffu + ((x >> 16) & 1u);     // RNE
  return (unsigned short)(x >> 16);
}
__device__ __forceinline__ void up8(const unsigned short* p, float* f){
  uint4 v = *(const uint4*)p;
  f[0]=blo(v.x); f[1]=bhi(v.x); f[2]=blo(v.y); f[3]=bhi(v.y);
  f[4]=blo(v.z); f[5]=bhi(v.z); f[6]=blo(v.w); f[7]=bhi(v.w);
}
__device__ __forceinline__ void async16(const void* g, void* l){
  __builtin_amdgcn_global_load_lds(
      (const __attribute__((address_space(1))) unsigned int*)g,
      (__attribute__((address_space(3))) unsigned int*)l, 16, 0, 0);
}

// ---------------- fused input cast + SumSq zeroing ------------------------
__global__ __launch_bounds__(256) void convert_all(
    const float* __restrict__ X,  const float* __restrict__ Wq,
    const float* __restrict__ Wk, const float* __restrict__ Wv,
    const float* __restrict__ Wg1,const float* __restrict__ Wg2,
    const float* __restrict__ gnw,const float* __restrict__ Wo,
    unsigned short* __restrict__ base, float* __restrict__ SumSq)
{
  int q = blockIdx.x * 256 + threadIdx.x;
  const float* src; unsigned short* dst; int rel = q;
  if (rel < 1048576)            { src = X;   dst = base;            }
  else if ((rel -= 1048576) < 262144) { src = Wq;  dst = base + 4194304; }
  else if ((rel -=  262144) < 262144) { src = Wk;  dst = base + 5242880; }
  else if ((rel -=  262144) < 262144) { src = Wv;  dst = base + 6291456; }
  else if ((rel -=  262144) < 262144) { src = Wo;  dst = base + 7340032; }
  else if ((rel -=  262144) <  32768) { src = Wg1; dst = base + 8388608; }
  else if ((rel -=   32768) <  32768) { src = Wg2; dst = base + 8519680; }
  else if ((rel -=   32768) <    256) { src = gnw; dst = base + 8650752; }
  else { rel -= 256;                              // zero SumSq (4096 floats)
    ((float4*)SumSq)[rel] = make_float4(0.f,0.f,0.f,0.f); return; }
  float4 v = ((const float4*)src)[rel];
  ushort4 o; o.x=f2bu(v.x); o.y=f2bu(v.y); o.z=f2bu(v.z); o.w=f2bu(v.w);
  ((ushort4*)dst)[rel] = o;
}

// ---------------- MFMA GEMM core: C(128x128)=A@B^T, BK=64 (2x32) ---------
__device__ __forceinline__ void gemm_core(
    const unsigned short* __restrict__ A, const unsigned short* __restrict__ B,
    int K, int row0, int col0,
    unsigned short* sA, unsigned short* sB, f32x4 acc[4][4], int tid)
{
  const int lane = tid & 63;
  const int wm = (tid >> 6) & 1, wn = tid >> 7;
  const int wb = tid & 192;                // wave-uniform chunk base
  for (int k0 = 0; k0 < K; k0 += 64){
    __syncthreads();                       // prev iter's LDS reads done
#pragma unroll
    for (int h = 0; h < 2; ++h){
#pragma unroll
      for (int r = 0; r < 2; ++r){
        int idx  = r*256 + tid;            // 512 chunks of 16B per sub-tile
        int mrow = idx >> 2, kc = (idx & 3) * 8;
        async16(A + (size_t)(row0 + mrow)*K + k0 + h*32 + kc,
                sA + (size_t)(h*512 + r*256 + wb)*8);
        async16(B + (size_t)(col0 + mrow)*K + k0 + h*32 + kc,
                sB + (size_t)(h*512 + r*256 + wb)*8);
      }
    }
    __syncthreads();                       // drains vmcnt before barrier
#pragma unroll
    for (int h = 0; h < 2; ++h){
      short8 av[4], bv[4];
#pragma unroll
      for (int i=0;i<4;i++)
        av[i] = *(const short8*)(sA + h*4096 + (size_t)(wm*64 + i*16 + (lane&15))*32 + (lane>>4)*8);
#pragma unroll
      for (int j=0;j<4;j++)
        bv[j] = *(const short8*)(sB + h*4096 + (size_t)(wn*64 + j*16 + (lane&15))*32 + (lane>>4)*8);
#pragma unroll
      for (int i=0;i<4;i++)
#pragma unroll
        for (int j=0;j<4;j++)
          acc[i][j] = __builtin_amdgcn_mfma_f32_16x16x32_bf16(av[i], bv[j], acc[i][j], 0, 0, 0);
    }
  }
}

// bf16 epilogue via LDS. act: 0 none, 1 silu/swish, 2 exp.
__device__ __forceinline__ void epilogue_lds(
    f32x4 acc[4][4], int row0, int col0, int tid, int ldc, int act,
    unsigned short* __restrict__ Cb, unsigned short* sC)
{
  const int lane = tid & 63;
  const int wm = (tid >> 6) & 1, wn = tid >> 7;
#pragma unroll
  for (int p=0;p<4;p++){
    __syncthreads();
    if (wm == (p>>1)){
#pragma unroll
      for (int ii=0; ii<2; ii++){
        int i = (p&1)*2 + ii;
        int lr = i*16 + ((lane>>4)<<2) - (p&1)*32;   // local row in [0,32)
#pragma unroll
        for (int j=0;j<4;j++){
          int col = wn*64 + j*16 + (lane&15);
#pragma unroll
          for (int r=0;r<4;r++){
            float v = acc[i][j][r];
            if (act == 1) v = v / (1.f + __expf(-v));
            else if (act == 2) v = __expf(v);
            sC[(lr+r)*128 + col] = f2bu(v);
          }
        }
      }
    }
    __syncthreads();
#pragma unroll
    for (int c = tid; c < 512; c += 256){  // 32 rows x 256B
      int rr = c >> 4, off = (c & 15)*8;
      *(uint4*)&Cb[(size_t)(row0 + p*32 + rr)*ldc + col0 + off] =
          *(const uint4*)&sC[rr*128 + off];
    }
  }
}

// fp32 direct epilogue (64B full-line segments).
__device__ __forceinline__ void epilogue_f32(
    f32x4 acc[4][4], int row0, int col0, int tid, int ldc,
    float* __restrict__ Cf)
{
  const int lane = tid & 63;
  const int wm = (tid >> 6) & 1, wn = tid >> 7;
#pragma unroll
  for (int i=0;i<4;i++){
    int rbase = row0 + wm*64 + i*16 + ((lane>>4)<<2);
#pragma unroll
    for (int j=0;j<4;j++){
      int col = col0 + wn*64 + j*16 + (lane&15);
#pragma unroll
      for (int r=0;r<4;r++)
        Cf[(size_t)(rbase + r)*ldc + col] = acc[i][j][r];
    }
  }
}

// Fused QKV+G1 projection. grid (32, 25): y<8 Q(silu), <16 K->e (exp),
// <24 V, ==24 G1.
__global__ __launch_bounds__(256, 4) void proj_kernel(
    const unsigned short* __restrict__ X,
    const unsigned short* __restrict__ Wq, const unsigned short* __restrict__ Wk,
    const unsigned short* __restrict__ Wv, const unsigned short* __restrict__ Wg1,
    unsigned short* __restrict__ Qb, unsigned short* __restrict__ Eb,
    unsigned short* __restrict__ Vb, unsigned short* __restrict__ G1b)
{
  __shared__ unsigned short sA[128*64], sB[128*64];
  int tid = threadIdx.x;
  int which = blockIdx.y >> 3;
  const unsigned short* Bp = (which==0)?Wq:(which==1)?Wk:(which==2)?Wv:Wg1;
  int row0 = blockIdx.x * 128;
  int col0 = (which==3) ? 0 : (blockIdx.y & 7) * 128;
  f32x4 acc[4][4] = {};
  gemm_core(X, Bp, HIDN, row0, col0, sA, sB, acc, tid);
  if      (which==0) epilogue_lds(acc,row0,col0,tid,HIDN,1,Qb, sA);
  else if (which==1) epilogue_lds(acc,row0,col0,tid,HIDN,2,Eb, sA);  // e=exp(k)
  else if (which==2) epilogue_lds(acc,row0,col0,tid,HIDN,0,Vb, sA);
  else               epilogue_lds(acc,row0,col0,tid,128 ,0,G1b,sA);
}

// Generic A@B^T. Cb nonnull -> bf16 LDS epilogue (act); else fp32 direct.
__global__ __launch_bounds__(256, 4) void gemm_bt(
    const unsigned short* __restrict__ A, const unsigned short* __restrict__ B,
    int K, int ldc, int act, float* __restrict__ Cf,
    unsigned short* __restrict__ Cb)
{
  __shared__ unsigned short sA[128*64], sB[128*64];
  int tid = threadIdx.x;
  int row0 = blockIdx.x * 128, col0 = blockIdx.y * 128;
  f32x4 acc[4][4] = {};
  gemm_core(A, B, K, row0, col0, sA, sB, acc, tid);
  if (Cb) epilogue_lds(acc, row0, col0, tid, ldc, act, Cb, sA);
  else    epilogue_f32(acc, row0, col0, tid, ldc, Cf);
}

// ---------------- pass 1 (MFMA): Esum[k], Ut[v][k] = sum_s V[s][v] e[s][k]
__global__ __launch_bounds__(512, 2) void attn_pass1(
    const unsigned short* __restrict__ Eb, const unsigned short* __restrict__ Vb,
    unsigned short* __restrict__ U, float* __restrict__ Esum)
{
  __shared__ unsigned short Vt[128*LDSP], Et[128*LDSP];   // ~70 KB
  __shared__ float seg_part[4*128];
  int tid = threadIdx.x;
  const int lane = tid & 63, quad = lane >> 4;
  const int w = tid >> 6, wm = w & 3, wn = w >> 2;
  const int Rb = wm*32, Cb = wn*64;
  int bh = blockIdx.x >> 4, ch = blockIdx.x & 15;
  int b = bh >> 3, h = bh & 7;
  size_t rowbase = (size_t)(b*T_SEQ + ch*128)*HIDN + h*128;

#pragma unroll
  for (int i=0;i<4;i++){                   // transpose-stage V and e
    int u = tid + i*512; int t = u >> 4, kc = (u & 15)*8;
    unsigned short tmp[8];
    *(uint4*)tmp = *(const uint4*)&Vb[rowbase + (size_t)t*HIDN + kc];
#pragma unroll
    for (int j=0;j<8;j++) Vt[(kc+j)*LDSP + t] = tmp[j];
    *(uint4*)tmp = *(const uint4*)&Eb[rowbase + (size_t)t*HIDN + kc];
#pragma unroll
    for (int j=0;j<8;j++) Et[(kc+j)*LDSP + t] = tmp[j];
  }
  __syncthreads();

  { // Esum[k] = row sums of Et
    int seg = tid >> 7, k = tid & 127;
    float s = 0.f;
    for (int c = seg*32; c < seg*32+32; ++c) s += bu2f(Et[k*LDSP + c]);
    seg_part[seg*128 + k] = s;
  }
  __syncthreads();
  if (tid < 128)
    Esum[(size_t)blockIdx.x*128 + tid] =
        seg_part[tid] + seg_part[128+tid] + seg_part[256+tid] + seg_part[384+tid];

  // Ut = Vt @ Et^T (contraction over s)
  f32x4 acc[2][4] = {};
  short8 av[2], bv[4];
#pragma unroll
  for (int s0=0; s0<128; s0+=32){
#pragma unroll
    for (int i=0;i<2;i++)
      av[i] = *(const short8*)(Vt + (Rb + i*16 + (lane&15))*LDSP + s0 + quad*8);
#pragma unroll
    for (int j=0;j<4;j++)
      bv[j] = *(const short8*)(Et + (Cb + j*16 + (lane&15))*LDSP + s0 + quad*8);
#pragma unroll
    for (int i=0;i<2;i++)
#pragma unroll
      for (int j=0;j<4;j++)
        acc[i][j] = __builtin_amdgcn_mfma_f32_16x16x32_bf16(av[i], bv[j], acc[i][j], 0,0,0);
  }
  __syncthreads();                         // all Et/Vt reads done

  // stage C (bf16) into Et region, coalesced copy-out
#pragma unroll
  for (int i=0;i<2;i++)
#pragma unroll
    for (int j=0;j<4;j++){
      int k = Cb + j*16 + (lane&15);
#pragma unroll
      for (int r=0;r<4;r++){
        int v = Rb + i*16 + quad*4 + r;
        Et[v*LDSP + k] = f2bu(acc[i][j][r]);
      }
    }
  __syncthreads();
  unsigned short* Ub = U + (size_t)blockIdx.x*16384;
#pragma unroll
  for (int i=0;i<4;i++){
    int u = tid + i*512; int v = u >> 4, kc = (u & 15)*8;
    *(uint4*)&Ub[v*128 + kc] = *(const uint4*)&Et[v*LDSP + kc];
  }
}

// ---------------- pass 2: exclusive prefix over chunks (in place) ----------
__global__ __launch_bounds__(256) void attn_pass2(
    unsigned short* __restrict__ U, float* __restrict__ Esum)
{
  int bh = blockIdx.x >> 4, sl = blockIdx.x & 15;
  int p = sl*1024 + threadIdx.x*4;
  float r0=0.f, r1=0.f, r2=0.f, r3=0.f;
  for (int c=0;c<16;c++){
    ushort4* ptr = (ushort4*)&U[(size_t)(bh*16 + c)*16384 + p];
    ushort4 t = *ptr;
    ushort4 w;
    w.x=f2bu(r0); w.y=f2bu(r1); w.z=f2bu(r2); w.w=f2bu(r3);
    *ptr = w;
    r0 += bu2f(t.x); r1 += bu2f(t.y); r2 += bu2f(t.z); r3 += bu2f(t.w);
  }
  if (sl == 0 && threadIdx.x < 128){
    float r = 0.f;
    for (int c=0;c<16;c++){
      float* q = &Esum[(size_t)(bh*16 + c)*128 + threadIdx.x];
      float t = *q; *q = r; r += t;
    }
  }
}

// ---------------- pass 3 (MFMA): o = qn@Cprev + causal(qn@e^T)@V + SumSq --
// 2 LDS buffers (68 KB -> 2 blocks/CU). Ut read DIRECT from global (no
// reuse; L2-resident). bufA: Q->qn->P->Ostage ; bufB: e->Vt.
__global__ __launch_bounds__(512, 4) void attn_pass3(
    const unsigned short* __restrict__ Eb, const unsigned short* __restrict__ Qb,
    const unsigned short* __restrict__ Vb, const unsigned short* __restrict__ U,
    const float* __restrict__ Esum, unsigned short* __restrict__ Oatt,
    float* __restrict__ SumSq)
{
  __shared__ unsigned short smem[2*128*LDSP];     // 68 KB
  __shared__ float seg_part[4*128];
  unsigned short* bufA = smem;
  unsigned short* bufB = smem + 128*LDSP;

  int tid = threadIdx.x;
  const int lane = tid & 63, quad = lane >> 4;
  const int w = tid >> 6, wm = w & 3, wn = w >> 2;
  const int Rb = wm*32, Cb = wn*64;
  int bh = blockIdx.x >> 4, ch = blockIdx.x & 15;
  int b = bh >> 3, h = bh & 7;
  size_t rowbase = (size_t)(b*T_SEQ + ch*128)*HIDN + h*128;
  const unsigned short* Ublk = U + (size_t)blockIdx.x*16384;

  // ---- stage Q, e ----
#pragma unroll
  for (int i=0;i<4;i++){
    int u = tid + i*512; int t = u >> 4, kc = (u & 15)*8;
    *(uint4*)&bufA[t*LDSP + kc] = *(const uint4*)&Qb[rowbase + (size_t)t*HIDN + kc];
    *(uint4*)&bufB[t*LDSP + kc] = *(const uint4*)&Eb[rowbase + (size_t)t*HIDN + kc];
  }
  __syncthreads();

  // ---- qn = q*SCALE/E_t ; 4-way segmented inclusive cumsum over t ----
  {
    int col = tid & 127, seg = tid >> 7;
    float psum = 0.f;
    for (int s = seg*32; s < seg*32+32; ++s) psum += bu2f(bufB[s*LDSP + col]);
    seg_part[seg*128 + col] = psum;
    __syncthreads();
    float run = Esum[(size_t)blockIdx.x*128 + col];
    for (int ss=0; ss<4; ++ss) if (ss < seg) run += seg_part[ss*128 + col];
    for (int s = seg*32; s < seg*32+32; ++s){
      run += bu2f(bufB[s*LDSP + col]);
      float q = bu2f(bufA[s*LDSP + col]);
      bufA[s*LDSP + col] = f2bu(q * SCALE * __builtin_amdgcn_rcpf(run));
    }
  }
  __syncthreads();

  // ---- inter: O = QN @ Ut^T (Ut direct from global) ; scores: P = QN@E^T --
  f32x4 accO[2][4] = {}, accP[2][4] = {};
  short8 av[2], bv[4];
#pragma unroll
  for (int k0=0; k0<128; k0+=32){
#pragma unroll
    for (int i=0;i<2;i++)
      av[i] = *(const short8*)(bufA + (Rb + i*16 + (lane&15))*LDSP + k0 + quad*8);
#pragma unroll
    for (int j=0;j<4;j++)
      bv[j] = *(const short8*)(Ublk + (size_t)(Cb + j*16 + (lane&15))*128 + k0 + quad*8);
#pragma unroll
    for (int i=0;i<2;i++)
#pragma unroll
      for (int j=0;j<4;j++)
        accO[i][j] = __builtin_amdgcn_mfma_f32_16x16x32_bf16(av[i], bv[j], accO[i][j], 0,0,0);
#pragma unroll
    for (int j=0;j<4;j++)
      bv[j] = *(const short8*)(bufB + (Cb + j*16 + (lane&15))*LDSP + k0 + quad*8);
#pragma unroll
    for (int i=0;i<2;i++)
#pragma unroll
      for (int j=0;j<4;j++)
        accP[i][j] = __builtin_amdgcn_mfma_f32_16x16x32_bf16(av[i], bv[j], accP[i][j], 0,0,0);
  }
  __syncthreads();

  // ---- masked P -> bufA [t][s] ; V^T -> bufB [v][s] ----
#pragma unroll
  for (int i=0;i<2;i++){
#pragma unroll
    for (int j=0;j<4;j++){
      int s = Cb + j*16 + (lane&15);
#pragma unroll
      for (int r=0;r<4;r++){
        int t = Rb + i*16 + quad*4 + r;
        bufA[t*LDSP + s] = f2bu(s <= t ? accP[i][j][r] : 0.f);
      }
    }
  }
#pragma unroll
  for (int i=0;i<4;i++){
    int u = tid + i*512; int t = u >> 4, kc = (u & 15)*8;
    unsigned short tmp[8];
    *(uint4*)tmp = *(const uint4*)&Vb[rowbase + (size_t)t*HIDN + kc];
#pragma unroll
    for (int j=0;j<8;j++) bufB[(kc+j)*LDSP + t] = tmp[j];
  }
  __syncthreads();

  // ---- intra: O += P @ Vt^T ----
#pragma unroll
  for (int k0=0; k0<128; k0+=32){
#pragma unroll
    for (int i=0;i<2;i++)
      av[i] = *(const short8*)(bufA + (Rb + i*16 + (lane&15))*LDSP + k0 + quad*8);
#pragma unroll
    for (int j=0;j<4;j++)
      bv[j] = *(const short8*)(bufB + (Cb + j*16 + (lane&15))*LDSP + k0 + quad*8);
#pragma unroll
    for (int i=0;i<2;i++)
#pragma unroll
      for (int j=0;j<4;j++)
        accO[i][j] = __builtin_amdgcn_mfma_f32_16x16x32_bf16(av[i], bv[j], accO[i][j], 0,0,0);
  }
  __syncthreads();                        // all bufA (P) reads done

  // ---- O -> bufA (bf16) ----
#pragma unroll
  for (int i=0;i<2;i++){
#pragma unroll
    for (int j=0;j<4;j++){
      int v = Cb + j*16 + (lane&15);
#pragma unroll
      for (int r=0;r<4;r++){
        int t = Rb + i*16 + quad*4 + r;
        bufA[t*LDSP + v] = f2bu(accO[i][j][r]);
      }
    }
  }
  __syncthreads();

  // ---- per-row sum of squares (this head's 128 cols) ----
  {
    int seg = tid >> 7, row = tid & 127;
    float s = 0.f;
    for (int c = seg*32; c < seg*32+32; ++c){
      float x = bu2f(bufA[row*LDSP + c]); s += x*x;
    }
    seg_part[seg*128 + row] = s;
  }
  // ---- coalesced O write ----
#pragma unroll
  for (int i=0;i<4;i++){
    int u = tid + i*512; int t = u >> 4, kc = (u & 15)*8;
    *(uint4*)&Oatt[rowbase + (size_t)t*HIDN + kc] = *(const uint4*)&bufA[t*LDSP + kc];
  }
  __syncthreads();
  if (tid < 128){
    float s = seg_part[tid] + seg_part[128+tid] + seg_part[256+tid] + seg_part[384+tid];
    atomicAdd(&SumSq[(size_t)b*T_SEQ + ch*128 + tid], s);
  }
}

// ---- norm_gate2: elementwise RMSNorm(SumSq)*gnw*swish-gate -> bf16 -------
__global__ __launch_bounds__(256) void norm_gate2(
    const unsigned short* __restrict__ Oatt, const unsigned short* __restrict__ Gt,
    const unsigned short* __restrict__ gnw, const float* __restrict__ SumSq,
    unsigned short* __restrict__ Onorm)
{
  int row = blockIdx.x, tid = threadIdx.x;
  float rstd = rsqrtf(SumSq[row] * (1.f/1024.f) + 1e-5f);
  ushort4 o4 = *(const ushort4*)&Oatt[(size_t)row*HIDN + tid*4];
  ushort4 g4 = *(const ushort4*)&Gt  [(size_t)row*HIDN + tid*4];
  ushort4 w4 = *(const ushort4*)&gnw[tid*4];
  ushort4 r4;
  r4.x = f2bu(bu2f(o4.x) * rstd * bu2f(w4.x) * bu2f(g4.x));
  r4.y = f2bu(bu2f(o4.y) * rstd * bu2f(w4.y) * bu2f(g4.y));
  r4.z = f2bu(bu2f(o4.z) * rstd * bu2f(w4.z) * bu2f(g4.z));
  r4.w = f2bu(bu2f(o4.w) * rstd * bu2f(w4.w) * bu2f(g4.w));
  *(ushort4*)&Onorm[(size_t)row*HIDN + tid*4] = r4;
}

// ---------------- launch ----------------
extern "C" void kernel_launch(void* const* d_in, const int* in_sizes, int n_in,
                              void* d_out, int out_size, void* d_ws, size_t ws_size,
                              hipStream_t stream) {
  unsigned short* wsS = (unsigned short*)d_ws;     // ~69 MiB used

  unsigned short* Xc   = wsS;              // 4,194,304
  unsigned short* Wqc  = wsS + 4194304;
  unsigned short* Wkc  = wsS + 5242880;
  unsigned short* Wvc  = wsS + 6291456;
  unsigned short* Woc  = wsS + 7340032;
  unsigned short* Wg1c = wsS + 8388608;
  unsigned short* Wg2c = wsS + 8519680;
  unsigned short* gnwc = wsS + 8650752;
  unsigned short* Qb   = wsS + 8651776;
  unsigned short* Eb   = wsS + 12846080;   // e = exp(k), bf16
  unsigned short* Vb   = wsS + 17040384;
  unsigned short* G1b  = wsS + 21234688;
  unsigned short* Gt   = wsS + 21758976;
  unsigned short* Ub   = wsS + 25953280;
  unsigned short* Oattb= wsS + 30147584;
  float*          Esum = (float*)(wsS + 34341888);  // 32,768 floats
  float*          SumSq= (float*)(wsS + 34407424);  //  4,096 floats
  unsigned short* Onorm = Qb;              // Q dead after pass3

  convert_all<<<8453, 256, 0, stream>>>(
      (const float*)d_in[0], (const float*)d_in[1], (const float*)d_in[2],
      (const float*)d_in[3], (const float*)d_in[4], (const float*)d_in[5],
      (const float*)d_in[6], (const float*)d_in[7], wsS, SumSq);

  proj_kernel<<<dim3(32,25), 256, 0, stream>>>(Xc, Wqc, Wkc, Wvc, Wg1c, Qb, Eb, Vb, G1b);
  gemm_bt   <<<dim3(32,8),  256, 0, stream>>>(G1b, Wg2c, 128, HIDN, 1, nullptr, Gt);
  attn_pass1<<<256, 512, 0, stream>>>(Eb, Vb, Ub, Esum);
  attn_pass2<<<256, 256, 0, stream>>>(Ub, Esum);
  attn_pass3<<<256, 512, 0, stream>>>(Eb, Qb, Vb, Ub, Esum, Oattb, SumSq);
  norm_gate2<<<4096, 256, 0, stream>>>(Oattb, Gt, gnwc, SumSq, Onorm);
  gemm_bt   <<<dim3(32,8),  256, 0, stream>>>(Onorm, Woc, HIDN, HIDN, 0,
                                              (float*)d_out, nullptr);
}